// Round 10
// baseline (189.572 us; speedup 1.0000x reference)
//
#include <hip/hip_runtime.h>
#include <hip/hip_fp16.h>
#include <math.h>

#define BB 128
#define LL 512
#define KK 8
#define DD 300
#define D2 150          // D in fp16-pair units
#define CC 14
#define L_PER_BLOCK 8
#define UNROLL 4
#define NUM_LC (LL / L_PER_BLOCK)   // 64 partials per b

#define R_F4_ELEMS ((4905 * 300) / 4)   // 367875

typedef _Float16 h2 __attribute__((ext_vector_type(2)));

// prep: convert R fp32 -> fp16-pair table (2.94 MB, per-XCD-L2-resident).
__global__ __launch_bounds__(256) void prep(
    const float4* __restrict__ R4, h2* __restrict__ R16)
{
    const int i = blockIdx.x * 256 + threadIdx.x;
    if (i < R_F4_ELEMS) {
        const float4 f = R4[i];
        h2 a; a.x = (_Float16)f.x; a.y = (_Float16)f.y;
        h2 b; b.x = (_Float16)f.z; b.y = (_Float16)f.w;
        R16[2 * i]     = a;
        R16[2 * i + 1] = b;
    }
}

// Xp[lc][b][d] = sum_{l in chunk lc} [ (1-nn)*max_k(R[s_k,d]*e_k) + nn*R[m,d] ]
// Block = 8 l's. Phase 0: 64 threads gather this block's E values (random,
// HBM) + 8 N gates into LDS — latency absorbed by cross-block overlap.
// Phase 1: t<150 owns one fp16 pair of D; slave/master indices read at
// wave-uniform addresses (-> s_load); e via broadcast LDS reads;
// packed-fp16 mul/max, fp32 accumulate. No atomics: each block stores its
// private partial slice (coalesced float2).
__global__ __launch_bounds__(192) void gnn_agg(
    const int* __restrict__ master, const int* __restrict__ slaves,
    const int* __restrict__ edges, const float* __restrict__ E,
    const float* __restrict__ N, const h2* __restrict__ Rv,
    float2* __restrict__ Xp2)
{
    const int b  = blockIdx.x;
    const int lc = blockIdx.y;
    const int t  = threadIdx.x;
    const bool act = (t < D2);
    const int bl_base = b * LL + lc * L_PER_BLOCK;

    __shared__ __align__(16) int ebuf[L_PER_BLOCK * KK];
    __shared__ float nnbuf[L_PER_BLOCK];

    if (t < L_PER_BLOCK * KK) {                 // 64 random E gathers
        const _Float16 ev = (_Float16)E[edges[bl_base * KK + t]];
        h2 p; p.x = ev; p.y = ev;
        ebuf[t] = __builtin_bit_cast(int, p);
    } else if (t < L_PER_BLOCK * KK + L_PER_BLOCK) {
        const int l = t - L_PER_BLOCK * KK;
        nnbuf[l] = N[master[bl_base + l]];
    }
    __syncthreads();

    float accx = 0.f, accy = 0.f;

    for (int lg = 0; lg < L_PER_BLOCK; lg += UNROLL) {
        int   offm[UNROLL], offs[UNROLL][KK];
        int4  ea[UNROLL], eb2[UNROLL];
        float nn[UNROLL];

#pragma unroll
        for (int u = 0; u < UNROLL; ++u) {
            const int bl = bl_base + lg + u;
            offm[u] = master[bl] * D2;          // wave-uniform -> scalar
#pragma unroll
            for (int k = 0; k < KK; ++k)
                offs[u][k] = slaves[bl * KK + k] * D2;   // scalar
            ea[u]  = *(const int4*)&ebuf[(lg + u) * KK];     // broadcast LDS
            eb2[u] = *(const int4*)&ebuf[(lg + u) * KK + 4];
            nn[u]  = nnbuf[lg + u];
        }

        if (act) {
            h2 r[UNROLL][KK], rm[UNROLL];
#pragma unroll
            for (int u = 0; u < UNROLL; ++u) {
#pragma unroll
                for (int k = 0; k < KK; ++k) r[u][k] = (Rv + offs[u][k])[t];
            }
#pragma unroll
            for (int u = 0; u < UNROLL; ++u) rm[u] = (Rv + offm[u])[t];

#pragma unroll
            for (int u = 0; u < UNROLL; ++u) {
                const int ev[KK] = { ea[u].x, ea[u].y, ea[u].z, ea[u].w,
                                     eb2[u].x, eb2[u].y, eb2[u].z, eb2[u].w };
                h2 mx = r[u][0] * __builtin_bit_cast(h2, ev[0]);
#pragma unroll
                for (int k = 1; k < KK; ++k)
                    mx = __builtin_elementwise_max(
                        mx, r[u][k] * __builtin_bit_cast(h2, ev[k]));
                const float n = nn[u], a = 1.f - n;
                accx = fmaf(a, (float)mx.x, fmaf(n, (float)rm[u].x, accx));
                accy = fmaf(a, (float)mx.y, fmaf(n, (float)rm[u].y, accy));
            }
        }
    }
    if (act) Xp2[(lc * BB + b) * D2 + t] = make_float2(accx, accy);
}

// Reduce 64 partials -> x[b,:], then FC (300->14) + ReLU + softmax.
// One block per batch row; t<150 reduces one float2; 16 lanes per class dot.
__global__ __launch_bounds__(320) void fc_softmax(
    const float2* __restrict__ Xp2, const float* __restrict__ W,
    const float* __restrict__ bias, float* __restrict__ out)
{
    const int b = blockIdx.x;
    const int t = threadIdx.x;
    __shared__ float sx[DD];
    __shared__ float h[CC];

    if (t < D2) {
        float ax = 0.f, ay = 0.f;
        const float2* p = Xp2 + b * D2 + t;
#pragma unroll 8
        for (int lc = 0; lc < NUM_LC; ++lc) {
            const float2 v = p[(long)lc * BB * D2];
            ax += v.x; ay += v.y;
        }
        sx[2 * t]     = ax;
        sx[2 * t + 1] = ay;
    }
    __syncthreads();

    const int c = t >> 4;
    const int j = t & 15;
    if (c < CC) {
        float acc = 0.f;
        const float* w = W + c * DD;
        for (int d = j; d < DD; d += 16) acc += sx[d] * w[d];
#pragma unroll
        for (int off = 8; off > 0; off >>= 1) acc += __shfl_down(acc, off, 16);
        if (j == 0) h[c] = fmaxf(acc + bias[c], 0.f);
    }
    __syncthreads();
    if (t < CC) {
        float mx = -INFINITY;
#pragma unroll
        for (int i = 0; i < CC; ++i) mx = fmaxf(mx, h[i]);
        float s = 0.f;
#pragma unroll
        for (int i = 0; i < CC; ++i) s += expf(h[i] - mx);
        out[b * CC + t] = expf(h[t] - mx) / s;
    }
}

extern "C" void kernel_launch(void* const* d_in, const int* in_sizes, int n_in,
                              void* d_out, int out_size, void* d_ws, size_t ws_size,
                              hipStream_t stream) {
    const int*   master = (const int*)d_in[0];
    const int*   slaves = (const int*)d_in[1];
    const int*   edges  = (const int*)d_in[2];
    const float* R      = (const float*)d_in[3];
    const float* E      = (const float*)d_in[4];
    const float* N      = (const float*)d_in[5];
    const float* W      = (const float*)d_in[6];
    const float* bias   = (const float*)d_in[7];
    float* out = (float*)d_out;

    // ws layout (bytes): R16 [2,943,104] | X_part [NUM_LC*BB*DD*4 = 9,830,400]
    char* ws = (char*)d_ws;
    h2*     R16 = (h2*)ws;
    float2* Xp2 = (float2*)(ws + 2943104);

    prep<<<(R_F4_ELEMS + 255) / 256, 256, 0, stream>>>((const float4*)R, R16);

    dim3 grid(BB, NUM_LC);
    gnn_agg<<<grid, 192, 0, stream>>>(master, slaves, edges, E, N, R16, Xp2);

    fc_softmax<<<BB, 320, 0, stream>>>(Xp2, W, bias, out);
}

// Round 12
// 182.428 us; speedup vs baseline: 1.0392x; 1.0392x over previous
//
#include <hip/hip_runtime.h>
#include <hip/hip_fp16.h>
#include <math.h>

#define BB 128
#define LL 512
#define KK 8
#define DD 300
#define D2 150          // D in fp16-pair units
#define CC 14
#define L_PER_BLOCK 8
#define UNROLL 4
#define NUM_LC (LL / L_PER_BLOCK)   // 64 partials per b

#define R_F4_ELEMS ((4905 * 300) / 4)   // 367875

typedef _Float16 h2 __attribute__((ext_vector_type(2)));
typedef float    f4 __attribute__((ext_vector_type(4)));

// prep: convert R fp32 -> fp16-pair table (2.94 MB, per-XCD-L2-resident).
// R fp32 reads are touched once -> non-temporal to keep L2 clean for R16.
__global__ __launch_bounds__(256) void prep(
    const f4* __restrict__ R4, h2* __restrict__ R16)
{
    const int i = blockIdx.x * 256 + threadIdx.x;
    if (i < R_F4_ELEMS) {
        const f4 f = __builtin_nontemporal_load(R4 + i);
        h2 a; a.x = (_Float16)f.x; a.y = (_Float16)f.y;
        h2 b; b.x = (_Float16)f.z; b.y = (_Float16)f.w;
        R16[2 * i]     = a;
        R16[2 * i + 1] = b;
    }
}

// Xp[lc][b][d] = sum_{l in chunk lc} [ (1-nn)*max_k(R[s_k,d]*e_k) + nn*R[m,d] ]
// Block = 8 l's. Phase 0: 64 threads gather this block's E values (random,
// HBM, non-temporal: ~33MB of once-touched lines must not evict R16 from L2)
// + 8 N gates into LDS. Phase 1: t<150 owns one fp16 pair of D; index reads
// wave-uniform (-> s_load); packed-fp16 mul/max, fp32 accumulate; partial
// slice stored non-temporally (write-once stream).
__global__ __launch_bounds__(192) void gnn_agg(
    const int* __restrict__ master, const int* __restrict__ slaves,
    const int* __restrict__ edges, const float* __restrict__ E,
    const float* __restrict__ N, const h2* __restrict__ Rv,
    float2* __restrict__ Xp2)
{
    const int b  = blockIdx.x;
    const int lc = blockIdx.y;
    const int t  = threadIdx.x;
    const bool act = (t < D2);
    const int bl_base = b * LL + lc * L_PER_BLOCK;

    __shared__ __align__(16) int ebuf[L_PER_BLOCK * KK];
    __shared__ float nnbuf[L_PER_BLOCK];

    if (t < L_PER_BLOCK * KK) {                 // 64 random E gathers
        const int eidx = edges[bl_base * KK + t];
        const _Float16 ev = (_Float16)__builtin_nontemporal_load(E + eidx);
        h2 p; p.x = ev; p.y = ev;
        ebuf[t] = __builtin_bit_cast(int, p);
    } else if (t < L_PER_BLOCK * KK + L_PER_BLOCK) {
        const int l = t - L_PER_BLOCK * KK;
        nnbuf[l] = N[master[bl_base + l]];
    }
    __syncthreads();

    float accx = 0.f, accy = 0.f;

    for (int lg = 0; lg < L_PER_BLOCK; lg += UNROLL) {
        int   offm[UNROLL], offs[UNROLL][KK];
        int4  ea[UNROLL], eb2[UNROLL];
        float nn[UNROLL];

#pragma unroll
        for (int u = 0; u < UNROLL; ++u) {
            const int bl = bl_base + lg + u;
            offm[u] = master[bl] * D2;          // wave-uniform -> scalar
#pragma unroll
            for (int k = 0; k < KK; ++k)
                offs[u][k] = slaves[bl * KK + k] * D2;   // scalar
            ea[u]  = *(const int4*)&ebuf[(lg + u) * KK];     // broadcast LDS
            eb2[u] = *(const int4*)&ebuf[(lg + u) * KK + 4];
            nn[u]  = nnbuf[lg + u];
        }

        if (act) {
            h2 r[UNROLL][KK], rm[UNROLL];
#pragma unroll
            for (int u = 0; u < UNROLL; ++u) {
#pragma unroll
                for (int k = 0; k < KK; ++k) r[u][k] = (Rv + offs[u][k])[t];
            }
#pragma unroll
            for (int u = 0; u < UNROLL; ++u) rm[u] = (Rv + offm[u])[t];

#pragma unroll
            for (int u = 0; u < UNROLL; ++u) {
                const int ev[KK] = { ea[u].x, ea[u].y, ea[u].z, ea[u].w,
                                     eb2[u].x, eb2[u].y, eb2[u].z, eb2[u].w };
                h2 mx = r[u][0] * __builtin_bit_cast(h2, ev[0]);
#pragma unroll
                for (int k = 1; k < KK; ++k)
                    mx = __builtin_elementwise_max(
                        mx, r[u][k] * __builtin_bit_cast(h2, ev[k]));
                const float n = nn[u], a = 1.f - n;
                accx = fmaf(a, (float)mx.x, fmaf(n, (float)rm[u].x, accx));
                accy = fmaf(a, (float)mx.y, fmaf(n, (float)rm[u].y, accy));
            }
        }
    }
    if (act) {
        // write-once partial: non-temporal 8B store
        const float2 v = make_float2(accx, accy);
        __builtin_nontemporal_store(
            __builtin_bit_cast(unsigned long long, v),
            (unsigned long long*)(Xp2 + (lc * BB + b) * D2 + t));
    }
}

// Reduce 64 partials -> x[b,:], then FC (300->14) + ReLU + softmax.
// One block per batch row; t<150 reduces one float2; 16 lanes per class dot.
__global__ __launch_bounds__(320) void fc_softmax(
    const float2* __restrict__ Xp2, const float* __restrict__ W,
    const float* __restrict__ bias, float* __restrict__ out)
{
    const int b = blockIdx.x;
    const int t = threadIdx.x;
    __shared__ float sx[DD];
    __shared__ float h[CC];

    if (t < D2) {
        float ax = 0.f, ay = 0.f;
        const float2* p = Xp2 + b * D2 + t;
#pragma unroll 8
        for (int lc = 0; lc < NUM_LC; ++lc) {
            const float2 v = p[(long)lc * BB * D2];
            ax += v.x; ay += v.y;
        }
        sx[2 * t]     = ax;
        sx[2 * t + 1] = ay;
    }
    __syncthreads();

    const int c = t >> 4;
    const int j = t & 15;
    if (c < CC) {
        float acc = 0.f;
        const float* w = W + c * DD;
        for (int d = j; d < DD; d += 16) acc += sx[d] * w[d];
#pragma unroll
        for (int off = 8; off > 0; off >>= 1) acc += __shfl_down(acc, off, 16);
        if (j == 0) h[c] = fmaxf(acc + bias[c], 0.f);
    }
    __syncthreads();
    if (t < CC) {
        float mx = -INFINITY;
#pragma unroll
        for (int i = 0; i < CC; ++i) mx = fmaxf(mx, h[i]);
        float s = 0.f;
#pragma unroll
        for (int i = 0; i < CC; ++i) s += expf(h[i] - mx);
        out[b * CC + t] = expf(h[t] - mx) / s;
    }
}

extern "C" void kernel_launch(void* const* d_in, const int* in_sizes, int n_in,
                              void* d_out, int out_size, void* d_ws, size_t ws_size,
                              hipStream_t stream) {
    const int*   master = (const int*)d_in[0];
    const int*   slaves = (const int*)d_in[1];
    const int*   edges  = (const int*)d_in[2];
    const float* R      = (const float*)d_in[3];
    const float* E      = (const float*)d_in[4];
    const float* N      = (const float*)d_in[5];
    const float* W      = (const float*)d_in[6];
    const float* bias   = (const float*)d_in[7];
    float* out = (float*)d_out;

    // ws layout (bytes): R16 [2,943,104] | X_part [NUM_LC*BB*DD*4 = 9,830,400]
    char* ws = (char*)d_ws;
    h2*     R16 = (h2*)ws;
    float2* Xp2 = (float2*)(ws + 2943104);

    prep<<<(R_F4_ELEMS + 255) / 256, 256, 0, stream>>>((const f4*)R, R16);

    dim3 grid(BB, NUM_LC);
    gnn_agg<<<grid, 192, 0, stream>>>(master, slaves, edges, E, N, R16, Xp2);

    fc_softmax<<<BB, 320, 0, stream>>>(Xp2, W, bias, out);
}